// Round 11
// baseline (191.783 us; speedup 1.0000x reference)
//
#include <hip/hip_runtime.h>

// Problem constants
#define N_ROWS   32768      // 64*512 flattened z rows
#define KCODES   1024
#define DDIM     256
#define RPB      64         // rows per argmin block: As=64KB -> 2 blocks/CU
#define NBLK     512        // 32768/64

// d_out float offsets (outputs concatenated in reference return order)
#define O_ZQ     0                    // 8388608
#define O_LOSS   8388608              // 1
#define O_IDX    8388609              // 32768
#define O_NCS    8421377              // 1024
#define O_NEA    8422401              // 262144
#define O_NEMB   8684545              // 262144

// workspace float offsets
#define W_ESUM   0                    // 262144 (zeroed in k_prep2)
#define W_CNT    262144               // 1024 ints (zeroed in k_prep2)
#define W_DONE   263168               // 1024 ints (zeroed in k_prep2)
#define W_ENORM  264192               // 1024
#define W_LOSSP  265216               // 512
#define W_N      265728               // 1
#define W_IDX    265792               // 32768 ints
#define W_SORT   298560               // 32768 ints
#define W_RANK   331328               // 32768 ints (row's rank within its code)

typedef _Float16 half_t;
typedef __attribute__((ext_vector_type(8))) _Float16 half8;
typedef __attribute__((ext_vector_type(4))) float floatx4;

// ---------------------------------------------------------------------------
// Pack B into MFMA-native fragment order + compute ||e||^2.
// Layout: Bp[g16][pk][ns][lane][8]: g16 = cq*4+g4 (16), pk = packed k-step
// (16: e_hi 0..7 + e_lo 8..15), ns = 16-code subtile (4), lane (col=lane&15,
// k=(lane>>4)*8+j). Wave-step's 4 ns loads span one contiguous 4KB window.
// Also zeroes esum (1MB) + cnts/done (8KB).
__global__ __launch_bounds__(256)
void k_prep2(const float* __restrict__ emb, float* __restrict__ enorm,
             half_t* __restrict__ Bp, float* __restrict__ zero_ws) {
    __shared__ half_t hi[16 * 256];
    __shared__ half_t lo[16 * 256];
    __shared__ float  ssum[256];
    const int ct  = blockIdx.x;       // 16-code tile
    const int tid = threadIdx.x;
    const int c16 = tid >> 4;         // code within tile
    const int dp  = tid & 15;         // 16-dim part

    {   // zero esum (65536 f4) + cnts/done (512 f4)
        float4 z4 = {0.f, 0.f, 0.f, 0.f};
        float4* wsf4 = (float4*)zero_ws;
        int t = ct * 256 + tid;
        #pragma unroll
        for (int i = 0; i < 4; ++i) wsf4[t + i * 16384] = z4;
        if (t < 512) wsf4[65536 + t] = z4;
    }

    float ss = 0.f;
    #pragma unroll
    for (int i = 0; i < 4; ++i) {
        float4 v = *(const float4*)(emb + (size_t)(ct * 16 + c16) * DDIM + dp * 16 + i * 4);
        ss += v.x * v.x + v.y * v.y + v.z * v.z + v.w * v.w;
        #pragma unroll
        for (int q = 0; q < 4; ++q) {
            float f = (&v.x)[q];
            half_t h = (half_t)f;
            hi[c16 * 256 + dp * 16 + i * 4 + q] = h;
            lo[c16 * 256 + dp * 16 + i * 4 + q] = (half_t)(f - (float)h);
        }
    }
    ssum[tid] = ss;
    __syncthreads();
    if (tid < 16) {
        float s = 0.f;
        #pragma unroll
        for (int i = 0; i < 16; ++i) s += ssum[tid * 16 + i];
        enorm[ct * 16 + tid] = s;
    }

    // write phase: 16 packed steps x 64 lanes x 8 halfs
    const int g16 = ((ct >> 4) << 2) | ((ct >> 2) & 3);
    const int ns  = ct & 3;
    #pragma unroll
    for (int i = 0; i < 4; ++i) {
        int f    = tid + i * 256;     // 0..1023
        int ks   = f >> 6;            // pk 0..15
        int lane = f & 63;
        int cc   = lane & 15;
        int seg  = ks >> 3;           // 0:hi 1:lo
        int ko   = (ks & 7) * 32 + (lane >> 4) * 8;
        const half_t* src = (seg == 1) ? lo : hi;
        half8 v = *(const half8*)(src + cc * 256 + ko);
        *(half8*)(Bp + (((size_t)(g16 * 16 + ks) * 4 + ns) * 64 + lane) * 8) = v;
    }
}

// ---------------------------------------------------------------------------
// MFMA argmin. dist(r,c)=||e||^2-2 z.e; fp16 hi/lo 3-term split with paired
// phases. R11: the K-loop is a HALF-STEP PIPELINE — R10's PMC showed MfmaUtil
// 29% ~= duty cycle of the serial LDA->lgkmcnt->MFMA chain (latency-bound,
// not throughput: B-traffic halving in R10 changed nothing). Two A-buffers;
// every LDA is issued BEFORE the 8-MFMA block that hides its ~120cyc LDS
// latency. R7's A-efficient tiling (mt=2 x ns=4 = 0.25 LDS reads/MFMA).
// s_setprio(1) around MFMA clusters: waves here are barrier-free ->
// phase-diverse -> the attn-positive setprio case (guide m191), not the
// lockstep GEMM-null case (m190).
// PLAIN __launch_bounds__(512) — NO min-waves arg, EVER (2nd arg is a
// MINIMUM; allocator overshoots -> 64-VGPR cap -> 1.2GB spill).
__global__ __launch_bounds__(512)
void k_argmin(const float* __restrict__ z, const half_t* __restrict__ Bp,
              const float* __restrict__ enorm, const float* __restrict__ embf,
              int* __restrict__ out_idx, float* __restrict__ out_idx_f,
              float* __restrict__ out_zq, float* __restrict__ lossp,
              int* __restrict__ counts_i, int* __restrict__ rank_ws) {
    __shared__ __align__(16) half_t As[RPB * 512];   // 64 KB

    const int tid  = threadIdx.x;
    const int w    = tid >> 6;        // 0..7
    const int lane = tid & 63;
    const int tx   = lane & 15;
    const int quad = lane >> 4;
    const int rh   = w >> 2;          // row half: 0 -> rows 0..31, 1 -> 32..63
    const int cq   = w & 3;           // code quarter: codes [cq*256, cq*256+256)
    const int rbase = blockIdx.x * RPB;

    // ---- stage A: read z fp32, split hi/lo in-register, swizzled LDS store.
    {
        const int arow = w * 8 + (lane >> 3);   // 0..63, wave-local 8 rows
        const int sw   = arow & 7;
        #pragma unroll
        for (int it = 0; it < 4; ++it) {
            int g = it * 8 + (lane & 7);        // 0..31
            const float* zp = z + (size_t)(rbase + arow) * DDIM + g * 8;
            float4 v0 = *(const float4*)zp;
            float4 v1 = *(const float4*)(zp + 4);
            half8 hi, lo;
            hi[0] = (half_t)v0.x; lo[0] = (half_t)(v0.x - (float)hi[0]);
            hi[1] = (half_t)v0.y; lo[1] = (half_t)(v0.y - (float)hi[1]);
            hi[2] = (half_t)v0.z; lo[2] = (half_t)(v0.z - (float)hi[2]);
            hi[3] = (half_t)v0.w; lo[3] = (half_t)(v0.w - (float)hi[3]);
            hi[4] = (half_t)v1.x; lo[4] = (half_t)(v1.x - (float)hi[4]);
            hi[5] = (half_t)v1.y; lo[5] = (half_t)(v1.y - (float)hi[5]);
            hi[6] = (half_t)v1.z; lo[6] = (half_t)(v1.z - (float)hi[6]);
            hi[7] = (half_t)v1.w; lo[7] = (half_t)(v1.w - (float)hi[7]);
            *(half8*)(&As[arow * 512 + ((g ^ sw)) * 8])        = hi;  // k8 = g
            *(half8*)(&As[arow * 512 + (((32 + g) ^ sw)) * 8]) = lo;  // k8 = 32+g
        }
    }
    __syncthreads();                  // the ONLY main-loop barrier

    floatx4 zero4 = {0.f, 0.f, 0.f, 0.f};
    float bd[2][4];
    int   bi[2][4];
    #pragma unroll
    for (int mt = 0; mt < 2; ++mt)
        #pragma unroll
        for (int r = 0; r < 4; ++r) { bd[mt][r] = 3.402823466e38f; bi[mt][r] = 0; }

    for (int g4 = 0; g4 < 4; ++g4) {
        const int cb = cq * 256 + g4 * 64;
        const half_t* Bg = Bp + (size_t)(cq * 4 + g4) * 32768 + (size_t)lane * 8;

        floatx4 acc[2][4];
        #pragma unroll
        for (int mt = 0; mt < 2; ++mt)
            #pragma unroll
            for (int ns = 0; ns < 4; ++ns) acc[mt][ns] = zero4;

        half8 B0[4], B1[4];
        half8 a0[2], a1[2];
        #define LOADB(PK, BUF)                                                 \
            { const half_t* bp_ = Bg + (PK) * 2048;                            \
              _Pragma("unroll")                                                \
              for (int ns = 0; ns < 4; ++ns)                                   \
                  BUF[ns] = *(const half8*)(bp_ + ns * 512); }
        #define LDA(AF, K8)                                                    \
            _Pragma("unroll")                                                  \
            for (int mt = 0; mt < 2; ++mt) {                                   \
                int row = rh * 32 + mt * 16 + tx;                              \
                AF[mt] = *(half8*)(&As[row * 512 + (((K8) + quad) ^ (row & 7)) * 8]); \
            }
        #define MFMA_BLK(AF, BUF)                                              \
            __builtin_amdgcn_s_setprio(1);                                     \
            _Pragma("unroll")                                                  \
            for (int mt = 0; mt < 2; ++mt)                                     \
                _Pragma("unroll")                                              \
                for (int ns = 0; ns < 4; ++ns)                                 \
                    acc[mt][ns] = __builtin_amdgcn_mfma_f32_16x16x32_f16(      \
                        AF[mt], BUF[ns], acc[mt][ns], 0, 0, 0);                \
            __builtin_amdgcn_s_setprio(0);

        LOADB(0, B0);
        LOADB(1, B1);
        LDA(a0, 0)                               // z_hi(0)

        // hi phase s=0..7: B=e_hi(s), used twice; A reads pipelined one
        // half-step ahead (each LDA covered by the 8-MFMA block before use)
        #pragma unroll 2
        for (int s = 0; s < 8; ++s) {
            LDA(a1, 32 + s * 4)                  // prefetch z_lo(s)
            if (s & 1) { MFMA_BLK(a0, B1) } else { MFMA_BLK(a0, B0) }
            LDA(a0, ((s + 1) & 7) * 4)           // prefetch z_hi(s+1) (s==7 -> z_hi(0) for lo phase)
            if (s & 1) { MFMA_BLK(a1, B1) LOADB(s + 2, B1); }
            else       { MFMA_BLK(a1, B0) LOADB(s + 2, B0); }
        }
        // lo phase s=8..15: B=e_lo(s), A=z_hi(s-8); buffers alternate by s
        // parity (entering: a0 = z_hi(0) from the hi-phase prefetch)
        #pragma unroll 2
        for (int s = 8; s < 16; ++s) {
            if (s & 1) {
                if (s < 15) { LDA(a0, (s - 7) * 4) }   // prefetch z_hi(s-7)
                MFMA_BLK(a1, B1)
                if (s + 2 < 16) LOADB(s + 2, B1);
            } else {
                LDA(a1, (s - 7) * 4)                   // prefetch z_hi(s-7)
                MFMA_BLK(a0, B0)
                if (s + 2 < 16) LOADB(s + 2, B0);
            }
        }
        #undef LOADB
        #undef LDA
        #undef MFMA_BLK

        // fold group into running argmin (codes ascending; strict <, min-index)
        #pragma unroll
        for (int ns = 0; ns < 4; ++ns) {
            float en = enorm[cb + ns * 16 + tx];
            int   cc = cb + ns * 16 + tx;
            #pragma unroll
            for (int mt = 0; mt < 2; ++mt)
                #pragma unroll
                for (int r = 0; r < 4; ++r) {
                    float d = fmaf(-2.f, acc[mt][ns][r], en);
                    if (d < bd[mt][r]) { bd[mt][r] = d; bi[mt][r] = cc; }
                }
        }
    }

    // reduce across 16 tx lanes (same row, different codes); ties -> min index
    #pragma unroll
    for (int mt = 0; mt < 2; ++mt)
        #pragma unroll
        for (int r = 0; r < 4; ++r) {
            float d = bd[mt][r];
            int   b = bi[mt][r];
            #pragma unroll
            for (int off = 8; off > 0; off >>= 1) {
                float od = __shfl_xor(d, off);
                int   ob = __shfl_xor(b, off);
                if (od < d || (od == d && ob < b)) { d = od; b = ob; }
            }
            bd[mt][r] = d; bi[mt][r] = b;
        }

    // cross-wave reduce via LDS (reuse As): per row, 4 code-quarter candidates
    __syncthreads();
    float* sd   = (float*)As;          // [64 rows][4 quarters]
    int*   si   = ((int*)As) + 256;
    int*   sidx = ((int*)As) + 512;    // final idx per row
    if (tx == 0) {
        #pragma unroll
        for (int mt = 0; mt < 2; ++mt)
            #pragma unroll
            for (int r = 0; r < 4; ++r) {
                int row = rh * 32 + mt * 16 + quad * 4 + r;  // C-layout: row = quad*4+reg
                sd[row * 4 + cq] = bd[mt][r];
                si[row * 4 + cq] = bi[mt][r];
            }
    }
    __syncthreads();
    if (tid < RPB) {
        int row = tid;
        float d = sd[row * 4];
        int   b = si[row * 4];
        #pragma unroll
        for (int ww = 1; ww < 4; ++ww) {
            float od = sd[row * 4 + ww];
            int   ob = si[row * 4 + ww];
            if (od < d || (od == d && ob < b)) { d = od; b = ob; }
        }
        sidx[row] = b;
        out_idx[rbase + row]   = b;
        out_idx_f[rbase + row] = (float)b;
        int rk = atomicAdd(&counts_i[b], 1);   // rank of this row within code b
        rank_ws[rbase + row] = rk;
    }
    __syncthreads();

    // ---- fused z_q epilogue: z_q_st write + commitment-loss partial
    float l = 0.f;
    #pragma unroll
    for (int u = 0; u < 8; ++u) {
        int gi  = tid + u * 512;       // 0..4095 float4s = 64 rows x 64
        int row = gi >> 6;
        int c4  = gi & 63;
        int k   = sidx[row];           // wave-uniform
        float4 zv = *(const float4*)(z    + (size_t)(rbase + row) * DDIM + c4 * 4);
        float4 ev = *(const float4*)(embf + (size_t)k * DDIM + c4 * 4);
        float dx = ev.x - zv.x, dy = ev.y - zv.y, dz = ev.z - zv.z, dw = ev.w - zv.w;
        float4 o = { zv.x + dx, zv.y + dy, zv.z + dz, zv.w + dw };  // z + (z_q - z)
        *(float4*)(out_zq + (size_t)(rbase + row) * DDIM + c4 * 4) = o;
        l += dx * dx + dy * dy + dz * dz + dw * dw;
    }
    #pragma unroll
    for (int off = 32; off > 0; off >>= 1) l += __shfl_down(l, off);
    __shared__ float ls[8];
    if (lane == 0) ls[w] = l;
    __syncthreads();
    if (tid == 0) {
        float s = 0.f;
        #pragma unroll
        for (int i = 0; i < 8; ++i) s += ls[i];
        lossp[blockIdx.x] = s;
    }
}

// ---------------------------------------------------------------------------
// Fused scan+rank+empty-embed (R10-proven): every block redundantly
// LDS-scans counts (~2us), scatters its 256-row slice atomic-free, and
// writes embed outputs for EMPTY codes in its 8-code range. Block 0 emits
// ncs / n / loss. All work row- or code-O(1)-sliced -> skew-proof.
__global__ __launch_bounds__(256)
void k_scatter(const float* __restrict__ cs_in, const int* __restrict__ counts_i,
               const float* __restrict__ lossp, const int* __restrict__ idx,
               const int* __restrict__ rank_ws, const float* __restrict__ ea,
               int* __restrict__ rows_sorted,
               float* __restrict__ out_ncs, float* __restrict__ n_ws,
               float* __restrict__ loss_out,
               float* __restrict__ out_nea, float* __restrict__ out_nemb) {
    const int tid = threadIdx.x;
    const int bid = blockIdx.x;       // 128 blocks x 256 rows
    const int w    = tid >> 6;
    const int lane = tid & 63;
    __shared__ int ps[256];
    __shared__ int base_s[1024];
    __shared__ float sv[4], sl[4];

    int c[4]; int pt = 0;
    #pragma unroll
    for (int i = 0; i < 4; ++i) { c[i] = counts_i[tid * 4 + i]; pt += c[i]; }
    ps[tid] = pt;
    __syncthreads();
    for (int s = 1; s < 256; s <<= 1) {
        int v = (tid >= s) ? ps[tid - s] : 0;
        __syncthreads();
        ps[tid] += v;
        __syncthreads();
    }
    int o = ps[tid] - pt;              // exclusive base for this thread's 4 bins
    float pn = 0.f;
    #pragma unroll
    for (int i = 0; i < 4; ++i) {
        base_s[tid * 4 + i] = o;
        o += c[i];
        float nc = cs_in[tid * 4 + i] * 0.99f + 0.01f * (float)c[i];
        pn += nc;
        if (bid == 0) out_ncs[tid * 4 + i] = nc;
    }
    float pl = (bid == 0) ? (lossp[tid] + lossp[tid + 256]) : 0.f;
    #pragma unroll
    for (int off = 32; off > 0; off >>= 1) {
        pn += __shfl_down(pn, off);
        pl += __shfl_down(pl, off);
    }
    if (lane == 0) { sv[w] = pn; sl[w] = pl; }
    __syncthreads();                   // base_s + sv/sl ready
    const float nval = sv[0] + sv[1] + sv[2] + sv[3];
    if (bid == 0 && tid == 0) {
        n_ws[0]     = nval;
        loss_out[0] = 0.25f * ((sl[0] + sl[1] + sl[2] + sl[3]) / 8388608.0f);
    }
    {   // scatter this block's 256-row slice
        int r = bid * 256 + tid;
        int k = idx[r];
        rows_sorted[base_s[k] + rank_ws[r]] = r;
    }
    // empty-code embed: block owns codes bid*8..+7; 4 codes per pass
    #pragma unroll
    for (int pass = 0; pass < 2; ++pass) {
        int k = bid * 8 + pass * 4 + (tid >> 6);
        if (counts_i[k] == 0) {
            int l2 = tid & 63;
            size_t off = (size_t)k * DDIM + l2 * 4;
            float4 av = *(const float4*)(ea + off);
            float4 nea = { av.x * 0.99f, av.y * 0.99f, av.z * 0.99f, av.w * 0.99f };
            *(float4*)(out_nea + off) = nea;
            float ncv = cs_in[k] * 0.99f;
            float csv = (ncv + 1e-6f) / (nval + 0.001024f);
            float4 nemb = { nea.x / csv, nea.y / csv, nea.z / csv, nea.w / csv };
            *(float4*)(out_nemb + off) = nemb;
        }
    }
}

// ---------------------------------------------------------------------------
// Skew-proof segment-sum + LAST-FLUSHER embed (R10-proven). Each wave owns
// 32 sorted positions, run-accumulates in registers, flushes runs via fp32
// atomics, adds run length to done[code] after vmcnt(0) release. The wave
// completing done[k]==counts[k] reads esum back via atomicAdd(p,0)
// (coherent RMW) and writes nea/nemb for code k.
__global__ __launch_bounds__(256)
void k_esum3(const float* __restrict__ z, const int* __restrict__ rows_sorted,
             const int* __restrict__ idx, const int* __restrict__ counts_i,
             const float* __restrict__ cs_in, const float* __restrict__ n_ws,
             const float* __restrict__ ea, float* __restrict__ esum,
             int* __restrict__ done,
             float* __restrict__ out_nea, float* __restrict__ out_nemb) {
    const int tid  = threadIdx.x;
    const int w    = tid >> 6;        // 0..3
    const int lane = tid & 63;
    const int base = (blockIdx.x * 4 + w) * 32;   // 256 blocks x 4 waves x 32
    const float nval = n_ws[0];

    int r = rows_sorted[base + (lane & 31)];
    int c = idx[r];
    float4 acc = {0.f, 0.f, 0.f, 0.f};
    int rlen = 0;
    #pragma unroll 4
    for (int j = 0; j < 32; ++j) {
        int rj = __shfl(r, j);
        int cj = __shfl(c, j);
        float4 zv = *(const float4*)(z + (size_t)rj * DDIM + lane * 4);
        acc.x += zv.x; acc.y += zv.y; acc.z += zv.z; acc.w += zv.w;
        rlen++;
        int cn = (j < 31) ? __shfl(c, j + 1) : -1;
        if (cn != cj) {                // wave-uniform branch
            float* p = esum + (size_t)cj * DDIM + lane * 4;
            atomicAdd(p + 0, acc.x);
            atomicAdd(p + 1, acc.y);
            atomicAdd(p + 2, acc.z);
            atomicAdd(p + 3, acc.w);
            // release: esum adds must be globally done before done-update
            asm volatile("s_waitcnt vmcnt(0)" ::: "memory");
            int last = 0;
            if (lane == 0) {
                int old = atomicAdd(&done[cj], rlen);
                last = (old + rlen == counts_i[cj]) ? 1 : 0;
            }
            last = __shfl(last, 0);
            if (last) {                // this wave completed code cj -> embed
                float* q = esum + (size_t)cj * DDIM + lane * 4;
                float4 ev;
                ev.x = atomicAdd(q + 0, 0.f);
                ev.y = atomicAdd(q + 1, 0.f);
                ev.z = atomicAdd(q + 2, 0.f);
                ev.w = atomicAdd(q + 3, 0.f);
                size_t off = (size_t)cj * DDIM + lane * 4;
                float4 av = *(const float4*)(ea + off);
                float4 nea = { av.x * 0.99f + 0.01f * ev.x,
                               av.y * 0.99f + 0.01f * ev.y,
                               av.z * 0.99f + 0.01f * ev.z,
                               av.w * 0.99f + 0.01f * ev.w };
                *(float4*)(out_nea + off) = nea;
                float ncv = cs_in[cj] * 0.99f + 0.01f * (float)counts_i[cj];
                float csv = (ncv + 1e-6f) / (nval + 0.001024f);
                float4 nemb = { nea.x / csv, nea.y / csv, nea.z / csv, nea.w / csv };
                *(float4*)(out_nemb + off) = nemb;
            }
            acc.x = 0.f; acc.y = 0.f; acc.z = 0.f; acc.w = 0.f;
            rlen = 0;
        }
    }
}

// ---------------------------------------------------------------------------
extern "C" void kernel_launch(void* const* d_in, const int* in_sizes, int n_in,
                              void* d_out, int out_size, void* d_ws, size_t ws_size,
                              hipStream_t stream) {
    const float* z   = (const float*)d_in[0];
    const float* emb = (const float*)d_in[1];
    const float* cs  = (const float*)d_in[2];
    const float* ea  = (const float*)d_in[3];
    float* out = (float*)d_out;
    float* ws  = (float*)d_ws;

    float* esum    = ws + W_ESUM;
    int*   cnts    = (int*)(ws + W_CNT);
    int*   done    = (int*)(ws + W_DONE);
    float* enorm   = ws + W_ENORM;
    float* lossp   = ws + W_LOSSP;
    float* wn      = ws + W_N;
    int*   widx    = (int*)(ws + W_IDX);
    int*   rsorted = (int*)(ws + W_SORT);
    int*   rankw   = (int*)(ws + W_RANK);

    // packed-B fp16 scratch in dead O_NEA output region (16B-aligned;
    // k_scatter/k_esum3, the only writers of that region, run after argmin).
    half_t* Bp = (half_t*)(out + O_NEA + 3);   // 524288 halfs

    k_prep2   <<<64, 256, 0, stream>>>(emb, enorm, Bp, ws);
    k_argmin  <<<NBLK, 512, 0, stream>>>(z, Bp, enorm, emb,
                                         widx, out + O_IDX, out + O_ZQ, lossp,
                                         cnts, rankw);
    k_scatter <<<128, 256, 0, stream>>>(cs, cnts, lossp, widx, rankw, ea,
                                        rsorted, out + O_NCS, wn, out + O_LOSS,
                                        out + O_NEA, out + O_NEMB);
    k_esum3   <<<256, 256, 0, stream>>>(z, rsorted, widx, cnts, cs, wn, ea,
                                        esum, done, out + O_NEA, out + O_NEMB);
}

// Round 12
// 178.456 us; speedup vs baseline: 1.0747x; 1.0747x over previous
//
#include <hip/hip_runtime.h>

// Problem constants
#define N_ROWS   32768      // 64*512 flattened z rows
#define KCODES   1024
#define DDIM     256
#define RPB      64         // rows per argmin block: As=64KB -> 2 blocks/CU
#define NBLK     512        // 32768/64

// d_out float offsets (outputs concatenated in reference return order)
#define O_ZQ     0                    // 8388608
#define O_LOSS   8388608              // 1
#define O_IDX    8388609              // 32768
#define O_NCS    8421377              // 1024
#define O_NEA    8422401              // 262144
#define O_NEMB   8684545              // 262144

// workspace float offsets
#define W_ESUM   0                    // 262144 (zeroed in k_prep2)
#define W_CNT    262144               // 1024 ints (zeroed in k_prep2)
#define W_ENORM  263168               // 1024
#define W_LOSSP  264192               // 512
#define W_N      265728               // 1
#define W_IDX    265792               // 32768 ints
#define W_SORT   298560               // 32768 ints
#define W_RANK   331328               // 32768 ints (row's rank within its code)

typedef _Float16 half_t;
typedef __attribute__((ext_vector_type(8))) _Float16 half8;
typedef __attribute__((ext_vector_type(4))) float floatx4;

// ---------------------------------------------------------------------------
// Pack B into MFMA-native fragment order + compute ||e||^2.
// Layout (compact-addressing): Bp[g16][pk][ns][lane][8]:
//   g16 = cq*4+g4 (wave-group, 16), pk = packed k-step (16: e_hi pk 0..7 +
//   e_lo pk 8..15), ns = 16-code subtile (4), lane (col=lane&15,
//   k=(lane>>4)*8+j). A wave-step's 4 ns loads span one contiguous 4KB
//   window -> single address reg + imm offsets in k_argmin.
// Also zeroes esum (1MB) + cnts (4KB): 65792 float4 over 16384 threads.
__global__ __launch_bounds__(256)
void k_prep2(const float* __restrict__ emb, float* __restrict__ enorm,
             half_t* __restrict__ Bp, float* __restrict__ zero_ws) {
    __shared__ half_t hi[16 * 256];
    __shared__ half_t lo[16 * 256];
    __shared__ float  ssum[256];
    const int ct  = blockIdx.x;       // 16-code tile
    const int tid = threadIdx.x;
    const int c16 = tid >> 4;         // code within tile
    const int dp  = tid & 15;         // 16-dim part

    {   // zero esum + cnts (skew-proof tail needs esum=0: atomic run-flushes)
        float4 z4 = {0.f, 0.f, 0.f, 0.f};
        float4* wsf4 = (float4*)zero_ws;
        int t = ct * 256 + tid;
        #pragma unroll
        for (int i = 0; i < 4; ++i) wsf4[t + i * 16384] = z4;
        if (t < 256) wsf4[65536 + t] = z4;
    }

    float ss = 0.f;
    #pragma unroll
    for (int i = 0; i < 4; ++i) {
        float4 v = *(const float4*)(emb + (size_t)(ct * 16 + c16) * DDIM + dp * 16 + i * 4);
        ss += v.x * v.x + v.y * v.y + v.z * v.z + v.w * v.w;
        #pragma unroll
        for (int q = 0; q < 4; ++q) {
            float f = (&v.x)[q];
            half_t h = (half_t)f;
            hi[c16 * 256 + dp * 16 + i * 4 + q] = h;
            lo[c16 * 256 + dp * 16 + i * 4 + q] = (half_t)(f - (float)h);
        }
    }
    ssum[tid] = ss;
    __syncthreads();
    if (tid < 16) {
        float s = 0.f;
        #pragma unroll
        for (int i = 0; i < 16; ++i) s += ssum[tid * 16 + i];
        enorm[ct * 16 + tid] = s;
    }

    // write phase: 16 packed steps x 64 lanes x 8 halfs
    const int g16 = ((ct >> 4) << 2) | ((ct >> 2) & 3);
    const int ns  = ct & 3;
    #pragma unroll
    for (int i = 0; i < 4; ++i) {
        int f    = tid + i * 256;     // 0..1023
        int ks   = f >> 6;            // pk 0..15
        int lane = f & 63;
        int cc   = lane & 15;
        int seg  = ks >> 3;           // 0:hi 1:lo
        int ko   = (ks & 7) * 32 + (lane >> 4) * 8;
        const half_t* src = (seg == 1) ? lo : hi;
        half8 v = *(const half8*)(src + cc * 256 + ko);
        *(half8*)(Bp + (((size_t)(g16 * 16 + ks) * 4 + ns) * 64 + lane) * 8) = v;
    }
}

// ---------------------------------------------------------------------------
// MFMA argmin. dist(r,c)=||e||^2-2 z.e; fp16 hi/lo 3-term split:
// z.e ~= z_hi.e_hi + z_hi.e_lo + z_lo.e_hi.
// Paired phases (R5, proven R7 @75.6us): e_hi tiles (pk 0..7) loaded ONCE,
// MFMA'd twice (z_hi & z_lo) — 16 loads/wave-group instead of 24.
// Emits rank_ws[row] = atomicAdd(counts[code]) so the tail sort needs no
// second atomic pass.
// R11 LESSON (REVERTED): half-step SW pipeline + setprio = 84.7us, VGPR
// 60->76, Occupancy 32->20 — longer live ranges defeat the compiler's own
// scheduling; implicit 4-wave overlap already captures the gain (guide
// Common-mistake #5). Do NOT re-pipeline this loop at source level.
// PLAIN __launch_bounds__(512) — NO min-waves arg, EVER (the 2nd arg is a
// MINIMUM; allocator overshoots -> 64-VGPR cap -> 1.2GB scratch spill).
__global__ __launch_bounds__(512)
void k_argmin(const float* __restrict__ z, const half_t* __restrict__ Bp,
              const float* __restrict__ enorm, const float* __restrict__ embf,
              int* __restrict__ out_idx, float* __restrict__ out_idx_f,
              float* __restrict__ out_zq, float* __restrict__ lossp,
              int* __restrict__ counts_i, int* __restrict__ rank_ws) {
    __shared__ __align__(16) half_t As[RPB * 512];   // 64 KB

    const int tid  = threadIdx.x;
    const int w    = tid >> 6;        // 0..7
    const int lane = tid & 63;
    const int tx   = lane & 15;
    const int quad = lane >> 4;
    const int rh   = w >> 2;          // row half: 0 -> rows 0..31, 1 -> 32..63
    const int cq   = w & 3;           // code quarter: codes [cq*256, cq*256+256)
    const int rbase = blockIdx.x * RPB;

    // ---- stage A: read z fp32, split hi/lo in-register, swizzled LDS store.
    {
        const int arow = w * 8 + (lane >> 3);   // 0..63, wave-local 8 rows
        const int sw   = arow & 7;
        #pragma unroll
        for (int it = 0; it < 4; ++it) {
            int g = it * 8 + (lane & 7);        // 0..31
            const float* zp = z + (size_t)(rbase + arow) * DDIM + g * 8;
            float4 v0 = *(const float4*)zp;
            float4 v1 = *(const float4*)(zp + 4);
            half8 hi, lo;
            hi[0] = (half_t)v0.x; lo[0] = (half_t)(v0.x - (float)hi[0]);
            hi[1] = (half_t)v0.y; lo[1] = (half_t)(v0.y - (float)hi[1]);
            hi[2] = (half_t)v0.z; lo[2] = (half_t)(v0.z - (float)hi[2]);
            hi[3] = (half_t)v0.w; lo[3] = (half_t)(v0.w - (float)hi[3]);
            hi[4] = (half_t)v1.x; lo[4] = (half_t)(v1.x - (float)hi[4]);
            hi[5] = (half_t)v1.y; lo[5] = (half_t)(v1.y - (float)hi[5]);
            hi[6] = (half_t)v1.z; lo[6] = (half_t)(v1.z - (float)hi[6]);
            hi[7] = (half_t)v1.w; lo[7] = (half_t)(v1.w - (float)hi[7]);
            *(half8*)(&As[arow * 512 + ((g ^ sw)) * 8])        = hi;  // k8 = g
            *(half8*)(&As[arow * 512 + (((32 + g) ^ sw)) * 8]) = lo;  // k8 = 32+g
        }
    }
    __syncthreads();                  // the ONLY main-loop barrier

    floatx4 zero4 = {0.f, 0.f, 0.f, 0.f};
    float bd[2][4];
    int   bi[2][4];
    #pragma unroll
    for (int mt = 0; mt < 2; ++mt)
        #pragma unroll
        for (int r = 0; r < 4; ++r) { bd[mt][r] = 3.402823466e38f; bi[mt][r] = 0; }

    for (int g4 = 0; g4 < 4; ++g4) {
        const int cb = cq * 256 + g4 * 64;
        const half_t* Bg = Bp + (size_t)(cq * 4 + g4) * 32768 + (size_t)lane * 8;

        floatx4 acc[2][4];
        #pragma unroll
        for (int mt = 0; mt < 2; ++mt)
            #pragma unroll
            for (int ns = 0; ns < 4; ++ns) acc[mt][ns] = zero4;

        half8 B0[4], B1[4];
        #define LOADB(PK, BUF)                                                 \
            { const half_t* bp_ = Bg + (PK) * 2048;                            \
              _Pragma("unroll")                                                \
              for (int ns = 0; ns < 4; ++ns)                                   \
                  BUF[ns] = *(const half8*)(bp_ + ns * 512); }
        #define MFMA_BLK(AF, BUF)                                              \
            _Pragma("unroll")                                                  \
            for (int mt = 0; mt < 2; ++mt)                                     \
                _Pragma("unroll")                                              \
                for (int ns = 0; ns < 4; ++ns)                                 \
                    acc[mt][ns] = __builtin_amdgcn_mfma_f32_16x16x32_f16(      \
                        AF[mt], BUF[ns], acc[mt][ns], 0, 0, 0);

        LOADB(0, B0);
        LOADB(1, B1);

        // super-steps 0..7: B = e_hi pk s, used TWICE (z_hi & z_lo)
        #pragma unroll 2
        for (int s = 0; s < 8; ++s) {
            half8 a0[2], a1[2];
            #pragma unroll
            for (int mt = 0; mt < 2; ++mt) {
                int row = rh * 32 + mt * 16 + tx;
                int sw  = row & 7;
                a0[mt] = *(half8*)(&As[row * 512 + ((s * 4 + quad) ^ sw) * 8]);
                a1[mt] = *(half8*)(&As[row * 512 + ((32 + s * 4 + quad) ^ sw) * 8]);
            }
            if (s & 1) { MFMA_BLK(a0, B1) MFMA_BLK(a1, B1) LOADB(s + 2, B1); }
            else       { MFMA_BLK(a0, B0) MFMA_BLK(a1, B0) LOADB(s + 2, B0); }
        }
        // super-steps 8..15: B = e_lo pk s, used once (z_hi)
        #pragma unroll 2
        for (int s = 8; s < 16; ++s) {
            half8 a0[2];
            #pragma unroll
            for (int mt = 0; mt < 2; ++mt) {
                int row = rh * 32 + mt * 16 + tx;
                int sw  = row & 7;
                a0[mt] = *(half8*)(&As[row * 512 + (((s - 8) * 4 + quad) ^ sw) * 8]);
            }
            if (s & 1) { MFMA_BLK(a0, B1) if (s + 2 < 16) LOADB(s + 2, B1); }
            else       { MFMA_BLK(a0, B0) if (s + 2 < 16) LOADB(s + 2, B0); }
        }
        #undef LOADB
        #undef MFMA_BLK

        // fold group into running argmin (codes ascending; strict <, min-index)
        #pragma unroll
        for (int ns = 0; ns < 4; ++ns) {
            float en = enorm[cb + ns * 16 + tx];
            int   cc = cb + ns * 16 + tx;
            #pragma unroll
            for (int mt = 0; mt < 2; ++mt)
                #pragma unroll
                for (int r = 0; r < 4; ++r) {
                    float d = fmaf(-2.f, acc[mt][ns][r], en);
                    if (d < bd[mt][r]) { bd[mt][r] = d; bi[mt][r] = cc; }
                }
        }
    }

    // reduce across 16 tx lanes (same row, different codes); ties -> min index
    #pragma unroll
    for (int mt = 0; mt < 2; ++mt)
        #pragma unroll
        for (int r = 0; r < 4; ++r) {
            float d = bd[mt][r];
            int   b = bi[mt][r];
            #pragma unroll
            for (int off = 8; off > 0; off >>= 1) {
                float od = __shfl_xor(d, off);
                int   ob = __shfl_xor(b, off);
                if (od < d || (od == d && ob < b)) { d = od; b = ob; }
            }
            bd[mt][r] = d; bi[mt][r] = b;
        }

    // cross-wave reduce via LDS (reuse As): per row, 4 code-quarter candidates
    __syncthreads();
    float* sd   = (float*)As;          // [64 rows][4 quarters]
    int*   si   = ((int*)As) + 256;
    int*   sidx = ((int*)As) + 512;    // final idx per row
    if (tx == 0) {
        #pragma unroll
        for (int mt = 0; mt < 2; ++mt)
            #pragma unroll
            for (int r = 0; r < 4; ++r) {
                int row = rh * 32 + mt * 16 + quad * 4 + r;  // C-layout: row = quad*4+reg
                sd[row * 4 + cq] = bd[mt][r];
                si[row * 4 + cq] = bi[mt][r];
            }
    }
    __syncthreads();
    if (tid < RPB) {
        int row = tid;
        float d = sd[row * 4];
        int   b = si[row * 4];
        #pragma unroll
        for (int ww = 1; ww < 4; ++ww) {
            float od = sd[row * 4 + ww];
            int   ob = si[row * 4 + ww];
            if (od < d || (od == d && ob < b)) { d = od; b = ob; }
        }
        sidx[row] = b;
        out_idx[rbase + row]   = b;
        out_idx_f[rbase + row] = (float)b;
        int rk = atomicAdd(&counts_i[b], 1);   // rank of this row within code b
        rank_ws[rbase + row] = rk;
    }
    __syncthreads();

    // ---- fused z_q epilogue: z_q_st write + commitment-loss partial
    float l = 0.f;
    #pragma unroll
    for (int u = 0; u < 8; ++u) {
        int gi  = tid + u * 512;       // 0..4095 float4s = 64 rows x 64
        int row = gi >> 6;
        int c4  = gi & 63;
        int k   = sidx[row];           // wave-uniform
        float4 zv = *(const float4*)(z    + (size_t)(rbase + row) * DDIM + c4 * 4);
        float4 ev = *(const float4*)(embf + (size_t)k * DDIM + c4 * 4);
        float dx = ev.x - zv.x, dy = ev.y - zv.y, dz = ev.z - zv.z, dw = ev.w - zv.w;
        float4 o = { zv.x + dx, zv.y + dy, zv.z + dz, zv.w + dw };  // z + (z_q - z)
        *(float4*)(out_zq + (size_t)(rbase + row) * DDIM + c4 * 4) = o;
        l += dx * dx + dy * dy + dz * dz + dw * dw;
    }
    #pragma unroll
    for (int off = 32; off > 0; off >>= 1) l += __shfl_down(l, off);
    __shared__ float ls[8];
    if (lane == 0) ls[w] = l;
    __syncthreads();
    if (tid == 0) {
        float s = 0.f;
        #pragma unroll
        for (int i = 0; i < 8; ++i) s += ls[i];
        lossp[blockIdx.x] = s;
    }
}

// ---------------------------------------------------------------------------
// Fused scan+rank (saves one boundary vs R3): every block redundantly
// LDS-scans counts[1024] (~2us), then scatters its 256-row slice
// atomic-free: rows_sorted[base[k] + rank[r]] = r. Row-sliced -> skew-proof
// (R5 lesson: NOTHING in the tail may scale with per-code population).
// Block 0 additionally emits ncs / n / loss.
__global__ __launch_bounds__(256)
void k_scatter(const float* __restrict__ cs_in, const int* __restrict__ counts_i,
               const float* __restrict__ lossp, const int* __restrict__ idx,
               const int* __restrict__ rank_ws, int* __restrict__ rows_sorted,
               float* __restrict__ out_ncs, float* __restrict__ n_ws,
               float* __restrict__ loss_out) {
    const int tid = threadIdx.x;
    const int bid = blockIdx.x;       // 128 blocks x 256 rows
    __shared__ int ps[256];
    __shared__ int base_s[1024];
    __shared__ float sv[4], sl[4];

    int c[4]; int pt = 0;
    #pragma unroll
    for (int i = 0; i < 4; ++i) { c[i] = counts_i[tid * 4 + i]; pt += c[i]; }
    ps[tid] = pt;
    __syncthreads();
    for (int s = 1; s < 256; s <<= 1) {
        int v = (tid >= s) ? ps[tid - s] : 0;
        __syncthreads();
        ps[tid] += v;
        __syncthreads();
    }
    int o = ps[tid] - pt;              // exclusive base for this thread's 4 bins
    float v = 0.f;
    #pragma unroll
    for (int i = 0; i < 4; ++i) {
        base_s[tid * 4 + i] = o;
        o += c[i];
        if (bid == 0) {
            float nc = cs_in[tid * 4 + i] * 0.99f + 0.01f * (float)c[i];
            out_ncs[tid * 4 + i] = nc;
            v += nc;
        }
    }
    if (bid == 0) {
        float l = lossp[tid] + lossp[tid + 256];
        #pragma unroll
        for (int off = 32; off > 0; off >>= 1) {
            v += __shfl_down(v, off);
            l += __shfl_down(l, off);
        }
        if ((tid & 63) == 0) { sv[tid >> 6] = v; sl[tid >> 6] = l; }
    }
    __syncthreads();                   // base_s (and sv/sl) ready
    if (bid == 0 && tid == 0) {
        n_ws[0]     = sv[0] + sv[1] + sv[2] + sv[3];
        loss_out[0] = 0.25f * ((sl[0] + sl[1] + sl[2] + sl[3]) / 8388608.0f);
    }
    int r = bid * 256 + tid;
    int k = idx[r];
    rows_sorted[base_s[k] + rank_ws[r]] = r;
}

// ---------------------------------------------------------------------------
// Skew-proof segment-sum (R3/R7-proven): each wave owns exactly 32 sorted
// positions, accumulates equal-code runs in registers, flushes runs via
// fp32 atomics. Position-sliced -> perfectly balanced under any skew.
__global__ __launch_bounds__(256)
void k_esum2(const float* __restrict__ z, const int* __restrict__ rows_sorted,
             const int* __restrict__ idx, float* __restrict__ esum) {
    const int tid  = threadIdx.x;
    const int w    = tid >> 6;        // 0..3
    const int lane = tid & 63;
    const int base = (blockIdx.x * 4 + w) * 32;   // 256 blocks x 4 waves x 32

    int r = rows_sorted[base + (lane & 31)];
    int c = idx[r];
    float4 acc = {0.f, 0.f, 0.f, 0.f};
    #pragma unroll 8
    for (int j = 0; j < 32; ++j) {
        int rj = __shfl(r, j);
        int cj = __shfl(c, j);
        float4 zv = *(const float4*)(z + (size_t)rj * DDIM + lane * 4);
        acc.x += zv.x; acc.y += zv.y; acc.z += zv.z; acc.w += zv.w;
        int cn = (j < 31) ? __shfl(c, j + 1) : -1;
        if (cn != cj) {                // wave-uniform branch
            float* p = esum + (size_t)cj * DDIM + lane * 4;
            atomicAdd(p + 0, acc.x);
            atomicAdd(p + 1, acc.y);
            atomicAdd(p + 2, acc.z);
            atomicAdd(p + 3, acc.w);
            acc.x = 0.f; acc.y = 0.f; acc.z = 0.f; acc.w = 0.f;
        }
    }
}

// ---------------------------------------------------------------------------
// Embed: 256 blocks x 4 codes; thread t -> code kb+(t>>6), dims (t&63)*4.
__global__ __launch_bounds__(256)
void k_embed(const float* __restrict__ ea, const float* __restrict__ esum,
             const float* __restrict__ ncs, const float* __restrict__ n_ws,
             float* __restrict__ out_nea, float* __restrict__ out_nemb) {
    const int tid = threadIdx.x;
    const int kb  = blockIdx.x * 4;
    const int c   = tid >> 6;
    const int l   = tid & 63;
    size_t off = (size_t)(kb + c) * DDIM + l * 4;
    float4 av = *(const float4*)(ea   + off);
    float4 ev = *(const float4*)(esum + off);
    float4 nea = { av.x * 0.99f + 0.01f * ev.x,
                   av.y * 0.99f + 0.01f * ev.y,
                   av.z * 0.99f + 0.01f * ev.z,
                   av.w * 0.99f + 0.01f * ev.w };
    *(float4*)(out_nea + off) = nea;
    float csv = (ncs[kb + c] + 1e-6f) / (n_ws[0] + 0.001024f);  // (ncs+eps)/(n+K*eps)
    float4 nemb = { nea.x / csv, nea.y / csv, nea.z / csv, nea.w / csv };
    *(float4*)(out_nemb + off) = nemb;
}

// ---------------------------------------------------------------------------
extern "C" void kernel_launch(void* const* d_in, const int* in_sizes, int n_in,
                              void* d_out, int out_size, void* d_ws, size_t ws_size,
                              hipStream_t stream) {
    const float* z   = (const float*)d_in[0];
    const float* emb = (const float*)d_in[1];
    const float* cs  = (const float*)d_in[2];
    const float* ea  = (const float*)d_in[3];
    float* out = (float*)d_out;
    float* ws  = (float*)d_ws;

    float* esum    = ws + W_ESUM;
    int*   cnts    = (int*)(ws + W_CNT);
    float* enorm   = ws + W_ENORM;
    float* lossp   = ws + W_LOSSP;
    float* wn      = ws + W_N;
    int*   widx    = (int*)(ws + W_IDX);
    int*   rsorted = (int*)(ws + W_SORT);
    int*   rankw   = (int*)(ws + W_RANK);

    // packed-B fp16 scratch in dead O_NEA output region (16B-aligned;
    // k_embed, the only writer of that region, runs last). 1MB.
    half_t* Bp = (half_t*)(out + O_NEA + 3);   // 524288 halfs

    k_prep2   <<<64, 256, 0, stream>>>(emb, enorm, Bp, ws);
    k_argmin  <<<NBLK, 512, 0, stream>>>(z, Bp, enorm, emb,
                                         widx, out + O_IDX, out + O_ZQ, lossp,
                                         cnts, rankw);
    k_scatter <<<128, 256, 0, stream>>>(cs, cnts, lossp, widx, rankw, rsorted,
                                        out + O_NCS, wn, out + O_LOSS);
    k_esum2   <<<256, 256, 0, stream>>>(z, rsorted, widx, esum);
    k_embed   <<<256, 256, 0, stream>>>(ea, esum, out + O_NCS, wn,
                                        out + O_NEA, out + O_NEMB);
}

// Round 13
// 178.283 us; speedup vs baseline: 1.0757x; 1.0010x over previous
//
#include <hip/hip_runtime.h>

// Problem constants
#define N_ROWS   32768      // 64*512 flattened z rows
#define KCODES   1024
#define DDIM     256
#define RPB      32         // R13: rows per argmin block; As=32KB -> 4 blocks/CU
#define NBLK     1024       // 32768/32

// d_out float offsets (outputs concatenated in reference return order)
#define O_ZQ     0                    // 8388608
#define O_LOSS   8388608              // 1
#define O_IDX    8388609              // 32768
#define O_NCS    8421377              // 1024
#define O_NEA    8422401              // 262144
#define O_NEMB   8684545              // 262144

// workspace float offsets
#define W_ESUM   0                    // 262144 (zeroed in k_prep2)
#define W_CNT    262144               // 1024 ints (zeroed in k_prep2)
#define W_ENORM  263168               // 1024
#define W_LOSSP  264192               // 1024 (R13: one per argmin block)
#define W_N      265728               // 1
#define W_IDX    265792               // 32768 ints
#define W_SORT   298560               // 32768 ints
#define W_RANK   331328               // 32768 ints (row's rank within its code)

typedef _Float16 half_t;
typedef __attribute__((ext_vector_type(8))) _Float16 half8;
typedef __attribute__((ext_vector_type(4))) float floatx4;

// ---------------------------------------------------------------------------
// Pack B into MFMA-native fragment order + compute ||e||^2.
// Layout (compact-addressing): Bp[g16][pk][ns][lane][8]:
//   g16 slot covers codes [64*g16, 64*g16+64) (ascending), pk = packed
//   k-step (16: e_hi pk 0..7 + e_lo pk 8..15), ns = 16-code subtile (4),
//   lane (col=lane&15, k=(lane>>4)*8+j). A wave-step's 4 ns loads span one
//   contiguous 4KB window -> single address reg + imm offsets in k_argmin.
// Also zeroes esum (1MB) + cnts (4KB): 65792 float4 over 16384 threads.
__global__ __launch_bounds__(256)
void k_prep2(const float* __restrict__ emb, float* __restrict__ enorm,
             half_t* __restrict__ Bp, float* __restrict__ zero_ws) {
    __shared__ half_t hi[16 * 256];
    __shared__ half_t lo[16 * 256];
    __shared__ float  ssum[256];
    const int ct  = blockIdx.x;       // 16-code tile
    const int tid = threadIdx.x;
    const int c16 = tid >> 4;         // code within tile
    const int dp  = tid & 15;         // 16-dim part

    {   // zero esum + cnts (skew-proof tail needs esum=0: atomic run-flushes)
        float4 z4 = {0.f, 0.f, 0.f, 0.f};
        float4* wsf4 = (float4*)zero_ws;
        int t = ct * 256 + tid;
        #pragma unroll
        for (int i = 0; i < 4; ++i) wsf4[t + i * 16384] = z4;
        if (t < 256) wsf4[65536 + t] = z4;
    }

    float ss = 0.f;
    #pragma unroll
    for (int i = 0; i < 4; ++i) {
        float4 v = *(const float4*)(emb + (size_t)(ct * 16 + c16) * DDIM + dp * 16 + i * 4);
        ss += v.x * v.x + v.y * v.y + v.z * v.z + v.w * v.w;
        #pragma unroll
        for (int q = 0; q < 4; ++q) {
            float f = (&v.x)[q];
            half_t h = (half_t)f;
            hi[c16 * 256 + dp * 16 + i * 4 + q] = h;
            lo[c16 * 256 + dp * 16 + i * 4 + q] = (half_t)(f - (float)h);
        }
    }
    ssum[tid] = ss;
    __syncthreads();
    if (tid < 16) {
        float s = 0.f;
        #pragma unroll
        for (int i = 0; i < 16; ++i) s += ssum[tid * 16 + i];
        enorm[ct * 16 + tid] = s;
    }

    // write phase: 16 packed steps x 64 lanes x 8 halfs
    const int g16 = ((ct >> 4) << 2) | ((ct >> 2) & 3);
    const int ns  = ct & 3;
    #pragma unroll
    for (int i = 0; i < 4; ++i) {
        int f    = tid + i * 256;     // 0..1023
        int ks   = f >> 6;            // pk 0..15
        int lane = f & 63;
        int cc   = lane & 15;
        int seg  = ks >> 3;           // 0:hi 1:lo
        int ko   = (ks & 7) * 32 + (lane >> 4) * 8;
        const half_t* src = (seg == 1) ? lo : hi;
        half8 v = *(const half8*)(src + cc * 256 + ko);
        *(half8*)(Bp + (((size_t)(g16 * 16 + ks) * 4 + ns) * 64 + lane) * 8) = v;
    }
}

// ---------------------------------------------------------------------------
// MFMA argmin. dist(r,c)=||e||^2-2 z.e; fp16 hi/lo 3-term split:
// z.e ~= z_hi.e_hi + z_hi.e_lo + z_lo.e_hi, paired phases (e_hi loaded
// once, MFMA'd twice) — R7-proven math, bitwise identical results.
// R13 OCCUPANCY RESTRUCTURE: RPB 64->32 (As 64->32KB) so 4 blocks/CU fit;
// 8 waves x 4 blocks = 32 waves/CU = 8 waves/SIMD (was 4). Wave w owns all
// 32 rows x 128 codes (slots 2w,2w+1): same acc[2][4] register shape, same
// total MFMA / LDS-read / B-byte counts — work conserved, occupancy 2x.
// Targets the diagnosed latency-stall gap (75us vs ~27us pipe floor) via
// the mechanism that works (TLP), not source pipelining (R11: regressed).
// VGPR must stay <=64 (the 32-wave/CU boundary) — if the build lands 65+,
// waves halve and this is neutral, not a regression.
// PLAIN __launch_bounds__(512) — NO min-waves arg, EVER (the 2nd arg is a
// MINIMUM; allocator overshoots -> 64-VGPR cap -> 1.2GB scratch spill).
__global__ __launch_bounds__(512)
void k_argmin(const float* __restrict__ z, const half_t* __restrict__ Bp,
              const float* __restrict__ enorm, const float* __restrict__ embf,
              int* __restrict__ out_idx, float* __restrict__ out_idx_f,
              float* __restrict__ out_zq, float* __restrict__ lossp,
              int* __restrict__ counts_i, int* __restrict__ rank_ws) {
    __shared__ __align__(16) half_t As[RPB * 512];   // 32 KB

    const int tid  = threadIdx.x;
    const int w    = tid >> 6;        // 0..7
    const int lane = tid & 63;
    const int tx   = lane & 15;
    const int quad = lane >> 4;
    const int rbase = blockIdx.x * RPB;

    // ---- stage A: read z fp32, split hi/lo in-register, swizzled LDS store.
    // 32 rows x 32 g-slots = 1024 tasks over 512 threads (2 iterations).
    #pragma unroll
    for (int it = 0; it < 2; ++it) {
        int f   = tid + it * 512;
        int row = f >> 5;             // 0..31
        int g   = f & 31;
        const float* zp = z + (size_t)(rbase + row) * DDIM + g * 8;
        float4 v0 = *(const float4*)zp;
        float4 v1 = *(const float4*)(zp + 4);
        half8 hi, lo;
        hi[0] = (half_t)v0.x; lo[0] = (half_t)(v0.x - (float)hi[0]);
        hi[1] = (half_t)v0.y; lo[1] = (half_t)(v0.y - (float)hi[1]);
        hi[2] = (half_t)v0.z; lo[2] = (half_t)(v0.z - (float)hi[2]);
        hi[3] = (half_t)v0.w; lo[3] = (half_t)(v0.w - (float)hi[3]);
        hi[4] = (half_t)v1.x; lo[4] = (half_t)(v1.x - (float)hi[4]);
        hi[5] = (half_t)v1.y; lo[5] = (half_t)(v1.y - (float)hi[5]);
        hi[6] = (half_t)v1.z; lo[6] = (half_t)(v1.z - (float)hi[6]);
        hi[7] = (half_t)v1.w; lo[7] = (half_t)(v1.w - (float)hi[7]);
        int sw = row & 7;
        *(half8*)(&As[row * 512 + ((g ^ sw)) * 8])        = hi;  // k8 = g
        *(half8*)(&As[row * 512 + (((32 + g) ^ sw)) * 8]) = lo;  // k8 = 32+g
    }
    __syncthreads();                  // the ONLY main-loop barrier

    floatx4 zero4 = {0.f, 0.f, 0.f, 0.f};
    float bd[2][4];
    int   bi[2][4];
    #pragma unroll
    for (int mt = 0; mt < 2; ++mt)
        #pragma unroll
        for (int r = 0; r < 4; ++r) { bd[mt][r] = 3.402823466e38f; bi[mt][r] = 0; }

    // wave w owns slots 2w, 2w+1 (codes [128w, 128w+128), ascending in w)
    for (int gs = 0; gs < 2; ++gs) {
        const int slot = 2 * w + gs;
        const int cb   = slot * 64;
        const half_t* Bg = Bp + (size_t)slot * 32768 + (size_t)lane * 8;

        floatx4 acc[2][4];
        #pragma unroll
        for (int mt = 0; mt < 2; ++mt)
            #pragma unroll
            for (int ns = 0; ns < 4; ++ns) acc[mt][ns] = zero4;

        half8 B0[4], B1[4];
        #define LOADB(PK, BUF)                                                 \
            { const half_t* bp_ = Bg + (PK) * 2048;                            \
              _Pragma("unroll")                                                \
              for (int ns = 0; ns < 4; ++ns)                                   \
                  BUF[ns] = *(const half8*)(bp_ + ns * 512); }
        #define MFMA_BLK(AF, BUF)                                              \
            _Pragma("unroll")                                                  \
            for (int mt = 0; mt < 2; ++mt)                                     \
                _Pragma("unroll")                                              \
                for (int ns = 0; ns < 4; ++ns)                                 \
                    acc[mt][ns] = __builtin_amdgcn_mfma_f32_16x16x32_f16(      \
                        AF[mt], BUF[ns], acc[mt][ns], 0, 0, 0);

        LOADB(0, B0);
        LOADB(1, B1);

        // super-steps 0..7: B = e_hi pk s, used TWICE (z_hi & z_lo)
        #pragma unroll 2
        for (int s = 0; s < 8; ++s) {
            half8 a0[2], a1[2];
            #pragma unroll
            for (int mt = 0; mt < 2; ++mt) {
                int row = mt * 16 + tx;
                int sw  = row & 7;
                a0[mt] = *(half8*)(&As[row * 512 + ((s * 4 + quad) ^ sw) * 8]);
                a1[mt] = *(half8*)(&As[row * 512 + ((32 + s * 4 + quad) ^ sw) * 8]);
            }
            if (s & 1) { MFMA_BLK(a0, B1) MFMA_BLK(a1, B1) LOADB(s + 2, B1); }
            else       { MFMA_BLK(a0, B0) MFMA_BLK(a1, B0) LOADB(s + 2, B0); }
        }
        // super-steps 8..15: B = e_lo pk s, used once (z_hi)
        #pragma unroll 2
        for (int s = 8; s < 16; ++s) {
            half8 a0[2];
            #pragma unroll
            for (int mt = 0; mt < 2; ++mt) {
                int row = mt * 16 + tx;
                int sw  = row & 7;
                a0[mt] = *(half8*)(&As[row * 512 + (((s - 8) * 4 + quad) ^ sw) * 8]);
            }
            if (s & 1) { MFMA_BLK(a0, B1) if (s + 2 < 16) LOADB(s + 2, B1); }
            else       { MFMA_BLK(a0, B0) if (s + 2 < 16) LOADB(s + 2, B0); }
        }
        #undef LOADB
        #undef MFMA_BLK

        // fold group into running argmin (codes ascending; strict <, min-index)
        #pragma unroll
        for (int ns = 0; ns < 4; ++ns) {
            float en = enorm[cb + ns * 16 + tx];
            int   cc = cb + ns * 16 + tx;
            #pragma unroll
            for (int mt = 0; mt < 2; ++mt)
                #pragma unroll
                for (int r = 0; r < 4; ++r) {
                    float d = fmaf(-2.f, acc[mt][ns][r], en);
                    if (d < bd[mt][r]) { bd[mt][r] = d; bi[mt][r] = cc; }
                }
        }
    }

    // reduce across 16 tx lanes (same row, different codes); ties -> min index
    #pragma unroll
    for (int mt = 0; mt < 2; ++mt)
        #pragma unroll
        for (int r = 0; r < 4; ++r) {
            float d = bd[mt][r];
            int   b = bi[mt][r];
            #pragma unroll
            for (int off = 8; off > 0; off >>= 1) {
                float od = __shfl_xor(d, off);
                int   ob = __shfl_xor(b, off);
                if (od < d || (od == d && ob < b)) { d = od; b = ob; }
            }
            bd[mt][r] = d; bi[mt][r] = b;
        }

    // cross-wave reduce via LDS (reuse As): per row, 8 wave candidates
    // (wave w covers codes 128w.. ascending -> ascending ww scan keeps
    // the global min-index tie-break)
    __syncthreads();
    float* sd   = (float*)As;          // [32 rows][8 waves]
    int*   si   = ((int*)As) + 256;
    int*   sidx = ((int*)As) + 512;    // final idx per row
    if (tx == 0) {
        #pragma unroll
        for (int mt = 0; mt < 2; ++mt)
            #pragma unroll
            for (int r = 0; r < 4; ++r) {
                int row = mt * 16 + quad * 4 + r;  // C-layout: row = quad*4+reg
                sd[row * 8 + w] = bd[mt][r];
                si[row * 8 + w] = bi[mt][r];
            }
    }
    __syncthreads();
    if (tid < RPB) {
        int row = tid;
        float d = sd[row * 8];
        int   b = si[row * 8];
        #pragma unroll
        for (int ww = 1; ww < 8; ++ww) {
            float od = sd[row * 8 + ww];
            int   ob = si[row * 8 + ww];
            if (od < d || (od == d && ob < b)) { d = od; b = ob; }
        }
        sidx[row] = b;
        out_idx[rbase + row]   = b;
        out_idx_f[rbase + row] = (float)b;
        int rk = atomicAdd(&counts_i[b], 1);   // rank of this row within code b
        rank_ws[rbase + row] = rk;
    }
    __syncthreads();

    // ---- fused z_q epilogue: z_q_st write + commitment-loss partial
    float l = 0.f;
    #pragma unroll
    for (int u = 0; u < 4; ++u) {
        int gi  = tid + u * 512;       // 0..2047 float4s = 32 rows x 64
        int row = gi >> 6;
        int c4  = gi & 63;
        int k   = sidx[row];           // wave-uniform
        float4 zv = *(const float4*)(z    + (size_t)(rbase + row) * DDIM + c4 * 4);
        float4 ev = *(const float4*)(embf + (size_t)k * DDIM + c4 * 4);
        float dx = ev.x - zv.x, dy = ev.y - zv.y, dz = ev.z - zv.z, dw = ev.w - zv.w;
        float4 o = { zv.x + dx, zv.y + dy, zv.z + dz, zv.w + dw };  // z + (z_q - z)
        *(float4*)(out_zq + (size_t)(rbase + row) * DDIM + c4 * 4) = o;
        l += dx * dx + dy * dy + dz * dz + dw * dw;
    }
    #pragma unroll
    for (int off = 32; off > 0; off >>= 1) l += __shfl_down(l, off);
    __shared__ float ls[8];
    if (lane == 0) ls[w] = l;
    __syncthreads();
    if (tid == 0) {
        float s = 0.f;
        #pragma unroll
        for (int i = 0; i < 8; ++i) s += ls[i];
        lossp[blockIdx.x] = s;
    }
}

// ---------------------------------------------------------------------------
// Fused scan+rank (R7-proven): every block redundantly LDS-scans
// counts[1024] (~2us), then scatters its 256-row slice atomic-free:
// rows_sorted[base[k] + rank[r]] = r. Row-sliced -> skew-proof (R5 lesson).
// Block 0 additionally emits ncs / n / loss (lossp now 1024 entries).
__global__ __launch_bounds__(256)
void k_scatter(const float* __restrict__ cs_in, const int* __restrict__ counts_i,
               const float* __restrict__ lossp, const int* __restrict__ idx,
               const int* __restrict__ rank_ws, int* __restrict__ rows_sorted,
               float* __restrict__ out_ncs, float* __restrict__ n_ws,
               float* __restrict__ loss_out) {
    const int tid = threadIdx.x;
    const int bid = blockIdx.x;       // 128 blocks x 256 rows
    __shared__ int ps[256];
    __shared__ int base_s[1024];
    __shared__ float sv[4], sl[4];

    int c[4]; int pt = 0;
    #pragma unroll
    for (int i = 0; i < 4; ++i) { c[i] = counts_i[tid * 4 + i]; pt += c[i]; }
    ps[tid] = pt;
    __syncthreads();
    for (int s = 1; s < 256; s <<= 1) {
        int v = (tid >= s) ? ps[tid - s] : 0;
        __syncthreads();
        ps[tid] += v;
        __syncthreads();
    }
    int o = ps[tid] - pt;              // exclusive base for this thread's 4 bins
    float v = 0.f;
    #pragma unroll
    for (int i = 0; i < 4; ++i) {
        base_s[tid * 4 + i] = o;
        o += c[i];
        if (bid == 0) {
            float nc = cs_in[tid * 4 + i] * 0.99f + 0.01f * (float)c[i];
            out_ncs[tid * 4 + i] = nc;
            v += nc;
        }
    }
    if (bid == 0) {
        float l = lossp[tid] + lossp[tid + 256] + lossp[tid + 512] + lossp[tid + 768];
        #pragma unroll
        for (int off = 32; off > 0; off >>= 1) {
            v += __shfl_down(v, off);
            l += __shfl_down(l, off);
        }
        if ((tid & 63) == 0) { sv[tid >> 6] = v; sl[tid >> 6] = l; }
    }
    __syncthreads();                   // base_s (and sv/sl) ready
    if (bid == 0 && tid == 0) {
        n_ws[0]     = sv[0] + sv[1] + sv[2] + sv[3];
        loss_out[0] = 0.25f * ((sl[0] + sl[1] + sl[2] + sl[3]) / 8388608.0f);
    }
    int r = bid * 256 + tid;
    int k = idx[r];
    rows_sorted[base_s[k] + rank_ws[r]] = r;
}

// ---------------------------------------------------------------------------
// Skew-proof segment-sum (R3/R7-proven): each wave owns exactly 32 sorted
// positions, accumulates equal-code runs in registers, flushes runs via
// fp32 atomics. Position-sliced -> perfectly balanced under any skew.
__global__ __launch_bounds__(256)
void k_esum2(const float* __restrict__ z, const int* __restrict__ rows_sorted,
             const int* __restrict__ idx, float* __restrict__ esum) {
    const int tid  = threadIdx.x;
    const int w    = tid >> 6;        // 0..3
    const int lane = tid & 63;
    const int base = (blockIdx.x * 4 + w) * 32;   // 256 blocks x 4 waves x 32

    int r = rows_sorted[base + (lane & 31)];
    int c = idx[r];
    float4 acc = {0.f, 0.f, 0.f, 0.f};
    #pragma unroll 8
    for (int j = 0; j < 32; ++j) {
        int rj = __shfl(r, j);
        int cj = __shfl(c, j);
        float4 zv = *(const float4*)(z + (size_t)rj * DDIM + lane * 4);
        acc.x += zv.x; acc.y += zv.y; acc.z += zv.z; acc.w += zv.w;
        int cn = (j < 31) ? __shfl(c, j + 1) : -1;
        if (cn != cj) {                // wave-uniform branch
            float* p = esum + (size_t)cj * DDIM + lane * 4;
            atomicAdd(p + 0, acc.x);
            atomicAdd(p + 1, acc.y);
            atomicAdd(p + 2, acc.z);
            atomicAdd(p + 3, acc.w);
            acc.x = 0.f; acc.y = 0.f; acc.z = 0.f; acc.w = 0.f;
        }
    }
}

// ---------------------------------------------------------------------------
// Embed: 256 blocks x 4 codes; thread t -> code kb+(t>>6), dims (t&63)*4.
__global__ __launch_bounds__(256)
void k_embed(const float* __restrict__ ea, const float* __restrict__ esum,
             const float* __restrict__ ncs, const float* __restrict__ n_ws,
             float* __restrict__ out_nea, float* __restrict__ out_nemb) {
    const int tid = threadIdx.x;
    const int kb  = blockIdx.x * 4;
    const int c   = tid >> 6;
    const int l   = tid & 63;
    size_t off = (size_t)(kb + c) * DDIM + l * 4;
    float4 av = *(const float4*)(ea   + off);
    float4 ev = *(const float4*)(esum + off);
    float4 nea = { av.x * 0.99f + 0.01f * ev.x,
                   av.y * 0.99f + 0.01f * ev.y,
                   av.z * 0.99f + 0.01f * ev.z,
                   av.w * 0.99f + 0.01f * ev.w };
    *(float4*)(out_nea + off) = nea;
    float csv = (ncs[kb + c] + 1e-6f) / (n_ws[0] + 0.001024f);  // (ncs+eps)/(n+K*eps)
    float4 nemb = { nea.x / csv, nea.y / csv, nea.z / csv, nea.w / csv };
    *(float4*)(out_nemb + off) = nemb;
}

// ---------------------------------------------------------------------------
extern "C" void kernel_launch(void* const* d_in, const int* in_sizes, int n_in,
                              void* d_out, int out_size, void* d_ws, size_t ws_size,
                              hipStream_t stream) {
    const float* z   = (const float*)d_in[0];
    const float* emb = (const float*)d_in[1];
    const float* cs  = (const float*)d_in[2];
    const float* ea  = (const float*)d_in[3];
    float* out = (float*)d_out;
    float* ws  = (float*)d_ws;

    float* esum    = ws + W_ESUM;
    int*   cnts    = (int*)(ws + W_CNT);
    float* enorm   = ws + W_ENORM;
    float* lossp   = ws + W_LOSSP;
    float* wn      = ws + W_N;
    int*   widx    = (int*)(ws + W_IDX);
    int*   rsorted = (int*)(ws + W_SORT);
    int*   rankw   = (int*)(ws + W_RANK);

    // packed-B fp16 scratch in dead O_NEA output region (16B-aligned;
    // k_embed, the only writer of that region, runs last). 1MB.
    half_t* Bp = (half_t*)(out + O_NEA + 3);   // 524288 halfs

    k_prep2   <<<64, 256, 0, stream>>>(emb, enorm, Bp, ws);
    k_argmin  <<<NBLK, 512, 0, stream>>>(z, Bp, enorm, emb,
                                         widx, out + O_IDX, out + O_ZQ, lossp,
                                         cnts, rankw);
    k_scatter <<<128, 256, 0, stream>>>(cs, cnts, lossp, widx, rankw, rsorted,
                                        out + O_NCS, wn, out + O_LOSS);
    k_esum2   <<<256, 256, 0, stream>>>(z, rsorted, widx, esum);
    k_embed   <<<256, 256, 0, stream>>>(ea, esum, out + O_NCS, wn,
                                        out + O_NEA, out + O_NEMB);
}